// Round 12
// baseline (175.253 us; speedup 1.0000x reference)
//
#include <hip/hip_runtime.h>

typedef _Float16 f16x8 __attribute__((ext_vector_type(8)));
typedef _Float16 f16x4 __attribute__((ext_vector_type(4)));
typedef short s16x4 __attribute__((ext_vector_type(4)));
typedef float f32x4 __attribute__((ext_vector_type(4)));

#define MFMA_K32(a, b, c) __builtin_amdgcn_mfma_f32_16x16x32_f16(a, b, c, 0, 0, 0)
#define MFMA_BF(a, b, c)  __builtin_amdgcn_mfma_f32_16x16x16bf16_1k(a, b, c, 0, 0, 0)
#define MFMA_F16(a, b, c) __builtin_amdgcn_mfma_f32_16x16x16f16(a, b, c, 0, 0, 0)

// B=8, N=3136, C=256, Ci=128, M=1568, NT=25088 rows. I/O fp32.
// Fragment-major internals:
//   theta_f [1568 tiles][kc 4][lane 64][8]          (f16)
//   phi_f [8][chunk 49][kvt 2][kc 4][lane 64][8]    (f16)
//   g_f   [8][chunk 49][ct 8][half 2][lane 64][4]   (bf16)
//   wt_f  [3][ct 8][kc 8][lane 64][8]               (f16)
//   wfT_f [ctile 16][lane 64][kc2 8][4]             (f16) == w_final^T A-frag
// Softmax: static-shift: p = exp2(s*log2e - 104), P/V bf16.
// ROUND-12: counted-vmcnt pipeline (T3+T4).  Five attn structures all
// pinned 62-65us at ~15% of issue floor; the loop is the exact "2-phase"
// shape whose measured overhead is ~72% stage+vmcnt(0)+barrier (m233).
// New loop: 4-buffer LDS ring (64KB), prefetch depth 2, raw s_barrier +
// counted s_waitcnt vmcnt(8) -- prefetch DMAs stay in flight ACROSS
// barriers; vmcnt never drains to 0 in the main loop (peeled tail 4/0).
// Ring-4/depth-2 is race-free: written buf is 3 steps from any reader
// (!=0 mod 4); each wave waits its own chunk-i loads before the collective
// barrier.  k_prep/k_proj = r11 verbatim (W-LDS-staged proj).

__device__ __forceinline__ f16x8 ld8f(const float* __restrict__ p) {
    f32x4 a = *(const f32x4*)p;
    f32x4 b = *(const f32x4*)(p + 4);
    f16x8 r;
    r[0] = (_Float16)a[0]; r[1] = (_Float16)a[1];
    r[2] = (_Float16)a[2]; r[3] = (_Float16)a[3];
    r[4] = (_Float16)b[0]; r[5] = (_Float16)b[1];
    r[6] = (_Float16)b[2]; r[7] = (_Float16)b[3];
    return r;
}
__device__ __forceinline__ unsigned f2bf_rne(float f) {
    unsigned u = __float_as_uint(f);
    return (u + 0x7FFFu + ((u >> 16) & 1u)) >> 16;
}
__device__ __forceinline__ int bfpack_rtz(float lo, float hi) {
    return (int)((__float_as_uint(hi) & 0xFFFF0000u) | (__float_as_uint(lo) >> 16));
}
__device__ __forceinline__ void gl_lds16(const _Float16* g, _Float16* l) {
    __builtin_amdgcn_global_load_lds(
        (const __attribute__((address_space(1))) unsigned*)g,
        (__attribute__((address_space(3))) unsigned*)l, 16, 0, 0);
}

// ---------------------------------------------------------------------------
// Prep: weights fp32 -> f16, fragment-major, gather-style (16B stores).
// grid 64, block 256.  (r11 verbatim)
// ---------------------------------------------------------------------------
__global__ __launch_bounds__(256) void k_prep(
    const float* __restrict__ wt, const float* __restrict__ wp,
    const float* __restrict__ wg, const float* __restrict__ wf,
    _Float16* __restrict__ wt_f, _Float16* __restrict__ wfT_f) {
    int i = blockIdx.x * 256 + threadIdx.x;  // 0..16383
    if (i < 12288) {
        int w    = i >> 12;
        int rem  = i & 4095;
        int ctkc = rem >> 6;          // ct*8+kc
        int l    = rem & 63;          // qq*16+tt
        const float* src = (w == 0) ? wt : (w == 1) ? wp : wg;
        const float* s = src + ((ctkc & 7) * 32 + (l >> 4) * 8) * 128
                             + (ctkc >> 3) * 16 + (l & 15);
        f16x8 v;
#pragma unroll
        for (int jj = 0; jj < 8; ++jj) v[jj] = (_Float16)s[jj * 128];
        *(f16x8*)(wt_f + i * 8) = v;
    } else {
        int j    = i - 12288;         // 0..4095
        int ct   = j >> 8;
        int rem  = j & 255;
        int qt   = rem >> 2;          // qq*16+tt
        int kc2e = rem & 3;
        int col  = ct * 16 + (qt & 15);
        int qq   = qt >> 4;
        f16x8 v;
#pragma unroll
        for (int jp = 0; jp < 8; ++jp) {
            int Ci = (kc2e * 2 + (jp >> 2)) * 16 + qq * 4 + (jp & 3);
            v[jp] = (_Float16)wf[Ci * 256 + col];
        }
        *(f16x8*)(wfT_f + j * 8) = v;
    }
}

// ---------------------------------------------------------------------------
// Projections.  grid (392, 3): blockIdx.y = weight matrix w; block = 4
// tiles x 1 matrix, wt_f[w] (64KB) staged in LDS once.  maxpool(2) fused.
// theta/phi: operand-swapped MFMA -> transposed D -> coalesced 8B stores.
// (r11 verbatim)
// ---------------------------------------------------------------------------
__global__ __launch_bounds__(256) void k_proj(
    const float* __restrict__ x,        // [25088][256] fp32
    const _Float16* __restrict__ wt_f,  // [3][8][8][512]
    _Float16* __restrict__ theta_f,     // [1568][2048]
    _Float16* __restrict__ phi_f,       // [8][49][4096]
    short* __restrict__ g_f)            // [8][49][8][2][64][4] bf16
{
    const int w    = blockIdx.y;
    const int wave = threadIdx.x >> 6;
    const int lane = threadIdx.x & 63;
    const int q = lane >> 4, t = lane & 15;
    const int tt = blockIdx.x * 4 + wave;   // tile 0..1567

    __shared__ __align__(16) _Float16 Wl[32768];  // 64 KB
    {
        const _Float16* src = wt_f + w * 32768;
#pragma unroll
        for (int j = 0; j < 16; ++j) {
            const int o8 = (j * 256 + threadIdx.x) * 8;
            *(f16x8*)(Wl + o8) = *(const f16x8*)(src + o8);
        }
    }
    __syncthreads();

    const int mrow = tt * 16 + t;
    f16x8 af[8];
#pragma unroll
    for (int kc = 0; kc < 8; ++kc)
        af[kc] = ld8f(x + mrow * 256 + kc * 32 + q * 8);

    const f32x4 zero = {0.f, 0.f, 0.f, 0.f};
    f32x4 acc[8];
#pragma unroll
    for (int ct = 0; ct < 8; ++ct) acc[ct] = zero;

    if (w == 2) {
        // g: original orientation D[i=xrow=4q+r][j=Ci=ct*16+t]
#pragma unroll
        for (int ct = 0; ct < 8; ++ct) {
            const _Float16* Wc = Wl + (ct * 8) * 512 + lane * 8;
#pragma unroll
            for (int kc = 0; kc < 8; ++kc)
                acc[ct] = MFMA_K32(af[kc], *(const f16x8*)(Wc + kc * 512), acc[ct]);
        }
    } else {
        // theta/phi: swapped -> D[i=Ci16=4q+r][j=xrow=t]
#pragma unroll
        for (int ct = 0; ct < 8; ++ct) {
            const _Float16* Wc = Wl + (ct * 8) * 512 + lane * 8;
#pragma unroll
            for (int kc = 0; kc < 8; ++kc)
                acc[ct] = MFMA_K32(*(const f16x8*)(Wc + kc * 512), af[kc], acc[ct]);
        }
    }

    if (w == 0) {
        // theta^T[Ci=ct*16+4q+r][row=t] -> B-frag halves, 8B stores
        _Float16* tb = theta_f + tt * 2048;
#pragma unroll
        for (int ct = 0; ct < 8; ++ct) {
            f16x4 v;
#pragma unroll
            for (int r = 0; r < 4; ++r) v[r] = (_Float16)acc[ct][r];
            const int off = (ct >> 1) * 512
                          + (((ct & 1) * 2 + (q >> 1)) * 16 + t) * 8 + 4 * (q & 1);
            *(f16x4*)(tb + off) = v;
        }
        return;
    }

    const int b     = tt / 196;
    const int tl    = tt - b * 196;      // local tile 0..195
    const int chunk = tl >> 2;           // 0..48
    const int sub   = tl & 3;

    if (w == 1) {
        // pool xrow pairs (t, t^1) cross-lane; kv' = sub*8 + (t>>1)
        _Float16* pcb = phi_f + (b * 49 + chunk) * 4096;
#pragma unroll
        for (int ct = 0; ct < 8; ++ct) {
            f32x4 pm;
#pragma unroll
            for (int r = 0; r < 4; ++r)
                pm[r] = fmaxf(acc[ct][r], __shfl_xor(acc[ct][r], 1));
            if (!(t & 1)) {
                f16x4 v;
#pragma unroll
                for (int r = 0; r < 4; ++r) v[r] = (_Float16)pm[r];
                const int off = ((sub >> 1) * 4 + (ct >> 1)) * 512
                              + ((((ct & 1) * 2 + (q >> 1)) * 16)
                                 + (sub & 1) * 8 + (t >> 1)) * 8 + 4 * (q & 1);
                *(f16x4*)(pcb + off) = v;
            }
        }
    } else {
        // g layout: [ct][h][lane=qv*16+ci15][jj]  (4B stores)
        const int h   = sub >> 1;
        short* gcb = g_f + (b * 49 + chunk) * 4096;
        const int qv  = (sub & 1) * 2 + (q >> 1);
        const int jj0 = (q & 1) * 2;
#pragma unroll
        for (int ct = 0; ct < 8; ++ct) {
            unsigned lo = f2bf_rne(fmaxf(acc[ct][0], acc[ct][1]));
            unsigned hi = f2bf_rne(fmaxf(acc[ct][2], acc[ct][3]));
            *(unsigned*)(gcb + (ct * 2 + h) * 256 + (qv * 16 + t) * 4 + jj0) = lo | (hi << 16);
        }
    }
}

// ---------------------------------------------------------------------------
// Attention + fused w_final epilogue.  Counted-vmcnt pipelined loop:
// 4-buffer LDS ring, prefetch depth 2, raw s_barrier; vmcnt(8) steady
// state (8 DMAs in flight across the barrier), peeled tail 4/0.  Block =
// 2 m-tiles, wave (m=w>>1, h=w&1): tile m vs kv-half h; 2-barrier
// additive combine; epilogue ctiles split by h.  grid 784, block 256.
// ---------------------------------------------------------------------------
#define ISSUE(c) { const _Float16* s_ = src0 + (c) * 4096; \
    _Float16* d_ = &kv[(c) & 3][doff]; \
    _Pragma("unroll") for (int j = 0; j < 4; ++j) \
        gl_lds16(s_ + j * 512 + lane * 8, d_ + j * 512); }

#define COMPUTE(i) { \
    const _Float16* buf = &kv[(i) & 3][0]; \
    f32x4 st = zero; \
    __builtin_amdgcn_s_setprio(1); \
    _Pragma("unroll") for (int kc = 0; kc < 4; ++kc) { \
        f16x8 a = *(const f16x8*)(buf + (h * 4 + kc) * 512 + lane * 8); \
        st = MFMA_K32(a, qf[kc], st); \
    } \
    __builtin_amdgcn_s_setprio(0); \
    f32x4 pv; \
    _Pragma("unroll") for (int r = 0; r < 4; ++r) \
        pv[r] = exp2f(st[r] * L2E - SHIFT); \
    lsum += (pv[0] + pv[1]) + (pv[2] + pv[3]); \
    union { int i2[2]; s16x4 v; } u; \
    u.i2[0] = bfpack_rtz(pv[0], pv[1]); \
    u.i2[1] = bfpack_rtz(pv[2], pv[3]); \
    __builtin_amdgcn_s_setprio(1); \
    _Pragma("unroll") for (int ct = 0; ct < 8; ++ct) { \
        s16x4 vf = *(const s16x4*)(buf + 4096 + (ct * 2 + h) * 256 + lane * 4); \
        o[ct] = MFMA_BF(vf, u.v, o[ct]); \
    } \
    __builtin_amdgcn_s_setprio(0); }

__global__ __launch_bounds__(256) void k_attn(
    const _Float16* __restrict__ theta_f,  // [1568][2048]
    const _Float16* __restrict__ phi_f,    // [8][49][4096]
    const short* __restrict__ g_f,         // [8][49][4096] bf16
    const _Float16* __restrict__ wfT_f,    // [16][64][8][4]
    const float* __restrict__ x,           // [25088][256]
    float* __restrict__ out)               // [25088][256]
{
    const int blk  = blockIdx.x;          // 784 = 8 batches x 98
    const int b    = blk & 7;             // XCD affinity
    const int blkm = blk >> 3;            // 0..97
    const int wave = threadIdx.x >> 6;
    const int lane = threadIdx.x & 63;
    const int q = lane >> 4, t = lane & 15;
    const int m = wave >> 1;              // tile within block
    const int h = wave & 1;               // kv half

    __shared__ __align__(16) _Float16 kv[4][8192];  // 64 KB ring, 16KB/chunk
    __shared__ float lred[2][64];                   // 512 B

    const int tIdx0 = b * 196 + blkm * 2;           // block's 2 m-tiles
    const _Float16* ph = phi_f + b * 200704;
    const _Float16* gt = (const _Float16*)(g_f + b * 200704);

    f16x8 qf[4];
#pragma unroll
    for (int kc = 0; kc < 4; ++kc)
        qf[kc] = *(const f16x8*)(theta_f + (tIdx0 + m) * 2048 + kc * 512 + lane * 8);

    const f32x4 zero = {0.f, 0.f, 0.f, 0.f};
    f32x4 o[8];
#pragma unroll
    for (int ct = 0; ct < 8; ++ct) o[ct] = zero;
    float lsum = 0.f;
    const float L2E = 1.44269504f, SHIFT = 104.0f;

    // staging: wave w DMAs bytes [w*4KB, (w+1)*4KB) of each 16KB chunk.
    const _Float16* src0 = (wave < 2) ? (ph + wave * 2048) : (gt + (wave - 2) * 2048);
    const int doff = wave * 2048;

    ISSUE(0);
    ISSUE(1);

#pragma unroll 1
    for (int i = 0; i < 47; ++i) {
        ISSUE(i + 2);                      // 12 in flight
        asm volatile("s_waitcnt vmcnt(8)" ::: "memory");  // chunk i done
        __builtin_amdgcn_s_barrier();
        COMPUTE(i);
    }
    asm volatile("s_waitcnt vmcnt(4)" ::: "memory");      // chunk 47 done
    __builtin_amdgcn_s_barrier();
    COMPUTE(47);
    asm volatile("s_waitcnt vmcnt(0)" ::: "memory");      // chunk 48 done
    __builtin_amdgcn_s_barrier();
    COMPUTE(48);
    __syncthreads();                       // all compute done before scratch

    // combine halves (additive under static shift), 2 barriers
    float* cb = (float*)&kv[0][0];         // 16 KB scratch (= kv[0])
    if (h == 1) {
#pragma unroll
        for (int ct = 0; ct < 8; ++ct)
            *(f32x4*)&cb[m * 2048 + ct * 256 + lane * 4] = o[ct];
        lred[m][lane] = lsum;
    }
    __syncthreads();
    if (h == 0) {
#pragma unroll
        for (int ct = 0; ct < 8; ++ct)
            o[ct] += *(const f32x4*)&cb[m * 2048 + ct * 256 + lane * 4];
        lsum += lred[m][lane];
#pragma unroll
        for (int ct = 0; ct < 8; ++ct)
            *(f32x4*)&cb[m * 2048 + ct * 256 + lane * 4] = o[ct];
        lred[m][lane] = lsum;
    }
    __syncthreads();
    if (h == 1) {
#pragma unroll
        for (int ct = 0; ct < 8; ++ct)
            o[ct] = *(const f32x4*)&cb[m * 2048 + ct * 256 + lane * 4];
        lsum = lred[m][lane];
    }

    float lf = lsum;
    lf += __shfl_xor(lf, 16);
    lf += __shfl_xor(lf, 32);
    const float inv = 1.0f / lf;

    f16x4 yf[8];
#pragma unroll
    for (int ct = 0; ct < 8; ++ct)
#pragma unroll
        for (int r = 0; r < 4; ++r)
            yf[ct][r] = (_Float16)(o[ct][r] * inv);

    const int row = (tIdx0 + m) * 16 + t;
#pragma unroll 2
    for (int ci = 0; ci < 8; ++ci) {
        const int ctile = h * 8 + ci;
        union { f16x8 v8; f16x4 v4[2]; } w[4];
#pragma unroll
        for (int pp = 0; pp < 4; ++pp)
            w[pp].v8 = *(const f16x8*)(wfT_f + ctile * 2048 + lane * 32 + pp * 8);
        f32x4 acc = zero;
#pragma unroll
        for (int kc2 = 0; kc2 < 8; ++kc2)
            acc = MFMA_F16(w[kc2 >> 1].v4[kc2 & 1], yf[kc2], acc);
        const int col = ctile * 16 + q * 4;
        f32x4 xv = *(const f32x4*)(x + row * 256 + col);
        *(f32x4*)(out + row * 256 + col) = acc + xv;
    }
}

// ---------------------------------------------------------------------------
extern "C" void kernel_launch(void* const* d_in, const int* in_sizes, int n_in,
                              void* d_out, int out_size, void* d_ws, size_t ws_size,
                              hipStream_t stream) {
    const float* x  = (const float*)d_in[0];
    const float* wt = (const float*)d_in[1];
    const float* wp = (const float*)d_in[2];
    const float* wg = (const float*)d_in[3];
    const float* wf = (const float*)d_in[4];
    float* out = (float*)d_out;

    _Float16* ws      = (_Float16*)d_ws;
    _Float16* wt_f    = ws;               //  98304
    _Float16* wfT_f   = ws + 98304;       //  32768
    _Float16* theta_f = ws + 131072;      //  3211264
    _Float16* phi_f   = ws + 3342336;     //  1605632
    short*    g_f     = (short*)(ws + 4947968);  // 1605632
    // total 6553600 halves = ~13.1 MB

    k_prep<<<dim3(64),     256, 0, stream>>>(wt, wp, wg, wf, wt_f, wfT_f);
    k_proj<<<dim3(392, 3), 256, 0, stream>>>(x, wt_f, theta_f, phi_f, g_f);
    k_attn<<<dim3(784),    256, 0, stream>>>(theta_f, phi_f, g_f, wfT_f, x, out);
}

// Round 13
// 149.017 us; speedup vs baseline: 1.1761x; 1.1761x over previous
//
#include <hip/hip_runtime.h>

typedef _Float16 f16x8 __attribute__((ext_vector_type(8)));
typedef _Float16 f16x4 __attribute__((ext_vector_type(4)));
typedef short s16x4 __attribute__((ext_vector_type(4)));
typedef float f32x4 __attribute__((ext_vector_type(4)));

#define MFMA_K32(a, b, c) __builtin_amdgcn_mfma_f32_16x16x32_f16(a, b, c, 0, 0, 0)
#define MFMA_BF(a, b, c)  __builtin_amdgcn_mfma_f32_16x16x16bf16_1k(a, b, c, 0, 0, 0)
#define MFMA_F16(a, b, c) __builtin_amdgcn_mfma_f32_16x16x16f16(a, b, c, 0, 0, 0)

// B=8, N=3136, C=256, Ci=128, M=1568, NT=25088 rows. I/O fp32.
// Fragment-major internals:
//   theta_f [1568 tiles][kc 4][lane 64][8]          (f16)
//   phi_f [8][chunk 49][kvt 2][kc 4][lane 64][8]    (f16)
//   g_f   [8][chunk 49][ct 8][half 2][lane 64][4]   (bf16)
//   wt_f  [3][ct 8][kc 8][lane 64][8]               (f16)
//   wfT_f [ctile 16][lane 64][kc2 8][4]             (f16) == w_final^T A-frag
// Softmax: static-shift: p = exp2(s*log2e - 104), P/V bf16.
// ROUND-13: FINAL -- revert to the best-measured configuration (round 8,
// 150.8us total, session minimum).  Ledger: attn pinned 62-65us across 5
// structures + 4 technique grafts (occupancy x3 null; LDS-traffic /2 =
// -2.5us; gl_lds DMA null; setprio null; counted-vmcnt ring -24us
// REGRESSION -- cross-block overlap beats intra-block pipeline depth on
// this kernel).  Residual ~87us invariant to 6 proj/prep rewrites; only
// W-LDS-staging moved it (-7us, confirmed twice); remainder believed
// harness reset dispatches.  No counter shows a roofline (MfmaUtil 20%,
// HBM 9%, conflicts 0) -- this is a latency-floor + fixed-overhead limit.

__device__ __forceinline__ f16x8 ld8f(const float* __restrict__ p) {
    f32x4 a = *(const f32x4*)p;
    f32x4 b = *(const f32x4*)(p + 4);
    f16x8 r;
    r[0] = (_Float16)a[0]; r[1] = (_Float16)a[1];
    r[2] = (_Float16)a[2]; r[3] = (_Float16)a[3];
    r[4] = (_Float16)b[0]; r[5] = (_Float16)b[1];
    r[6] = (_Float16)b[2]; r[7] = (_Float16)b[3];
    return r;
}
__device__ __forceinline__ unsigned f2bf_rne(float f) {
    unsigned u = __float_as_uint(f);
    return (u + 0x7FFFu + ((u >> 16) & 1u)) >> 16;
}
__device__ __forceinline__ int bfpack_rtz(float lo, float hi) {
    return (int)((__float_as_uint(hi) & 0xFFFF0000u) | (__float_as_uint(lo) >> 16));
}

// ---------------------------------------------------------------------------
// Prep: weights fp32 -> f16, fragment-major, gather-style (16B stores).
// grid 64, block 256.
// ---------------------------------------------------------------------------
__global__ __launch_bounds__(256) void k_prep(
    const float* __restrict__ wt, const float* __restrict__ wp,
    const float* __restrict__ wg, const float* __restrict__ wf,
    _Float16* __restrict__ wt_f, _Float16* __restrict__ wfT_f) {
    int i = blockIdx.x * 256 + threadIdx.x;  // 0..16383
    if (i < 12288) {
        int w    = i >> 12;
        int rem  = i & 4095;
        int ctkc = rem >> 6;          // ct*8+kc
        int l    = rem & 63;          // qq*16+tt
        const float* src = (w == 0) ? wt : (w == 1) ? wp : wg;
        const float* s = src + ((ctkc & 7) * 32 + (l >> 4) * 8) * 128
                             + (ctkc >> 3) * 16 + (l & 15);
        f16x8 v;
#pragma unroll
        for (int jj = 0; jj < 8; ++jj) v[jj] = (_Float16)s[jj * 128];
        *(f16x8*)(wt_f + i * 8) = v;
    } else {
        int j    = i - 12288;         // 0..4095
        int ct   = j >> 8;
        int rem  = j & 255;
        int qt   = rem >> 2;          // qq*16+tt
        int kc2e = rem & 3;
        int col  = ct * 16 + (qt & 15);
        int qq   = qt >> 4;
        f16x8 v;
#pragma unroll
        for (int jp = 0; jp < 8; ++jp) {
            int Ci = (kc2e * 2 + (jp >> 2)) * 16 + qq * 4 + (jp & 3);
            v[jp] = (_Float16)wf[Ci * 256 + col];
        }
        *(f16x8*)(wfT_f + j * 8) = v;
    }
}

// ---------------------------------------------------------------------------
// Projections.  grid (392, 3): blockIdx.y = weight matrix w; block = 4
// tiles x 1 matrix, wt_f[w] (64KB) staged in LDS once.  maxpool(2) fused.
// theta/phi: operand-swapped MFMA -> transposed D -> coalesced 8B stores.
// ---------------------------------------------------------------------------
__global__ __launch_bounds__(256) void k_proj(
    const float* __restrict__ x,        // [25088][256] fp32
    const _Float16* __restrict__ wt_f,  // [3][8][8][512]
    _Float16* __restrict__ theta_f,     // [1568][2048]
    _Float16* __restrict__ phi_f,       // [8][49][4096]
    short* __restrict__ g_f)            // [8][49][8][2][64][4] bf16
{
    const int w    = blockIdx.y;
    const int wave = threadIdx.x >> 6;
    const int lane = threadIdx.x & 63;
    const int q = lane >> 4, t = lane & 15;
    const int tt = blockIdx.x * 4 + wave;   // tile 0..1567

    __shared__ __align__(16) _Float16 Wl[32768];  // 64 KB
    {
        const _Float16* src = wt_f + w * 32768;
#pragma unroll
        for (int j = 0; j < 16; ++j) {
            const int o8 = (j * 256 + threadIdx.x) * 8;
            *(f16x8*)(Wl + o8) = *(const f16x8*)(src + o8);
        }
    }
    __syncthreads();

    const int mrow = tt * 16 + t;
    f16x8 af[8];
#pragma unroll
    for (int kc = 0; kc < 8; ++kc)
        af[kc] = ld8f(x + mrow * 256 + kc * 32 + q * 8);

    const f32x4 zero = {0.f, 0.f, 0.f, 0.f};
    f32x4 acc[8];
#pragma unroll
    for (int ct = 0; ct < 8; ++ct) acc[ct] = zero;

    if (w == 2) {
        // g: original orientation D[i=xrow=4q+r][j=Ci=ct*16+t]
#pragma unroll
        for (int ct = 0; ct < 8; ++ct) {
            const _Float16* Wc = Wl + (ct * 8) * 512 + lane * 8;
#pragma unroll
            for (int kc = 0; kc < 8; ++kc)
                acc[ct] = MFMA_K32(af[kc], *(const f16x8*)(Wc + kc * 512), acc[ct]);
        }
    } else {
        // theta/phi: swapped -> D[i=Ci16=4q+r][j=xrow=t]
#pragma unroll
        for (int ct = 0; ct < 8; ++ct) {
            const _Float16* Wc = Wl + (ct * 8) * 512 + lane * 8;
#pragma unroll
            for (int kc = 0; kc < 8; ++kc)
                acc[ct] = MFMA_K32(*(const f16x8*)(Wc + kc * 512), af[kc], acc[ct]);
        }
    }

    if (w == 0) {
        // theta^T[Ci=ct*16+4q+r][row=t] -> B-frag halves, 8B stores
        _Float16* tb = theta_f + tt * 2048;
#pragma unroll
        for (int ct = 0; ct < 8; ++ct) {
            f16x4 v;
#pragma unroll
            for (int r = 0; r < 4; ++r) v[r] = (_Float16)acc[ct][r];
            const int off = (ct >> 1) * 512
                          + (((ct & 1) * 2 + (q >> 1)) * 16 + t) * 8 + 4 * (q & 1);
            *(f16x4*)(tb + off) = v;
        }
        return;
    }

    const int b     = tt / 196;
    const int tl    = tt - b * 196;      // local tile 0..195
    const int chunk = tl >> 2;           // 0..48
    const int sub   = tl & 3;

    if (w == 1) {
        // pool xrow pairs (t, t^1) cross-lane; kv' = sub*8 + (t>>1)
        _Float16* pcb = phi_f + (b * 49 + chunk) * 4096;
#pragma unroll
        for (int ct = 0; ct < 8; ++ct) {
            f32x4 pm;
#pragma unroll
            for (int r = 0; r < 4; ++r)
                pm[r] = fmaxf(acc[ct][r], __shfl_xor(acc[ct][r], 1));
            if (!(t & 1)) {
                f16x4 v;
#pragma unroll
                for (int r = 0; r < 4; ++r) v[r] = (_Float16)pm[r];
                const int off = ((sub >> 1) * 4 + (ct >> 1)) * 512
                              + ((((ct & 1) * 2 + (q >> 1)) * 16)
                                 + (sub & 1) * 8 + (t >> 1)) * 8 + 4 * (q & 1);
                *(f16x4*)(pcb + off) = v;
            }
        }
    } else {
        // g layout: [ct][h][lane=qv*16+ci15][jj]  (4B stores)
        const int h   = sub >> 1;
        short* gcb = g_f + (b * 49 + chunk) * 4096;
        const int qv  = (sub & 1) * 2 + (q >> 1);
        const int jj0 = (q & 1) * 2;
#pragma unroll
        for (int ct = 0; ct < 8; ++ct) {
            unsigned lo = f2bf_rne(fmaxf(acc[ct][0], acc[ct][1]));
            unsigned hi = f2bf_rne(fmaxf(acc[ct][2], acc[ct][3]));
            *(unsigned*)(gcb + (ct * 2 + h) * 256 + (qv * 16 + t) * 4 + jj0) = lo | (hi << 16);
        }
    }
}

// ---------------------------------------------------------------------------
// Attention + fused w_final epilogue.  Block = 2 m-tiles, 4 waves:
// wave (m=wave>>1, h=wave&1) computes tile (tIdx0+m) against kv-half h of
// each staged chunk.  LDS dbuf staging (each wave copies 4KB of the 16KB
// chunk; prefetch overlaps compute; 1 barrier/chunk).  17KB LDS + 52 VGPR
// -> 3-4 blocks/CU co-resident (barriers overlap across blocks).  After
// scan: 2-barrier additive combine across h; epilogue ctiles split by h.
// grid 784 (8 b x 98), block 256.
// ---------------------------------------------------------------------------
__global__ __launch_bounds__(256) void k_attn(
    const _Float16* __restrict__ theta_f,  // [1568][2048]
    const _Float16* __restrict__ phi_f,    // [8][49][4096]
    const short* __restrict__ g_f,         // [8][49][4096] bf16
    const _Float16* __restrict__ wfT_f,    // [16][64][8][4]
    const float* __restrict__ x,           // [25088][256]
    float* __restrict__ out)               // [25088][256]
{
    const int blk  = blockIdx.x;          // 784 = 8 batches x 98
    const int b    = blk & 7;             // XCD affinity
    const int blkm = blk >> 3;            // 0..97
    const int wave = threadIdx.x >> 6;
    const int lane = threadIdx.x & 63;
    const int q = lane >> 4, t = lane & 15;
    const int m = wave >> 1;              // tile within block
    const int h = wave & 1;               // kv half

    __shared__ __align__(16) _Float16 kv[2][8192];  // 32 KB: [phi 4096 | g 4096]
    __shared__ float lred[2][64];                   // 512 B

    const int tIdx0 = b * 196 + blkm * 2;           // block's 2 m-tiles
    const _Float16* ph = phi_f + b * 200704;
    const _Float16* gt = (const _Float16*)(g_f + b * 200704);

    f16x8 qf[4];
#pragma unroll
    for (int kc = 0; kc < 4; ++kc)
        qf[kc] = *(const f16x8*)(theta_f + (tIdx0 + m) * 2048 + kc * 512 + lane * 8);

    const f32x4 zero = {0.f, 0.f, 0.f, 0.f};
    f32x4 o[8];
#pragma unroll
    for (int ct = 0; ct < 8; ++ct) o[ct] = zero;
    float lsum = 0.f;
    const float L2E = 1.44269504f, SHIFT = 104.0f;

    const _Float16* src0 = (wave < 2) ? (ph + wave * 2048) : (gt + (wave - 2) * 2048);
    const int doff = wave * 2048;

    f16x8 sr[4];
#pragma unroll
    for (int j = 0; j < 4; ++j)
        sr[j] = *(const f16x8*)(src0 + j * 512 + lane * 8);
#pragma unroll
    for (int j = 0; j < 4; ++j)
        *(f16x8*)(&kv[0][doff + j * 512 + lane * 8]) = sr[j];
    __syncthreads();

#pragma unroll 1
    for (int i = 0; i < 49; ++i) {
        if (i + 1 < 49) {
            const _Float16* s = src0 + (i + 1) * 4096;
#pragma unroll
            for (int j = 0; j < 4; ++j)
                sr[j] = *(const f16x8*)(s + j * 512 + lane * 8);
        }

        const _Float16* buf = &kv[i & 1][0];
        f32x4 st = zero;
#pragma unroll
        for (int kc = 0; kc < 4; ++kc) {
            f16x8 a = *(const f16x8*)(buf + (h * 4 + kc) * 512 + lane * 8);
            st = MFMA_K32(a, qf[kc], st);
        }

        f32x4 pv;
#pragma unroll
        for (int r = 0; r < 4; ++r)
            pv[r] = exp2f(st[r] * L2E - SHIFT);
        lsum += (pv[0] + pv[1]) + (pv[2] + pv[3]);
        union { int i2[2]; s16x4 v; } u;
        u.i2[0] = bfpack_rtz(pv[0], pv[1]);
        u.i2[1] = bfpack_rtz(pv[2], pv[3]);

#pragma unroll
        for (int ct = 0; ct < 8; ++ct) {
            s16x4 vf = *(const s16x4*)(buf + 4096 + (ct * 2 + h) * 256 + lane * 4);
            o[ct] = MFMA_BF(vf, u.v, o[ct]);
        }

        if (i + 1 < 49) {
            _Float16* d = &kv[(i + 1) & 1][doff];
#pragma unroll
            for (int j = 0; j < 4; ++j)
                *(f16x8*)(d + j * 512 + lane * 8) = sr[j];
        }
        __syncthreads();
    }

    // combine halves (additive under static shift), 2 barriers
    float* cb = (float*)&kv[0][0];       // 16 KB scratch: tile m gets 8 KB
    if (h == 1) {
#pragma unroll
        for (int ct = 0; ct < 8; ++ct)
            *(f32x4*)&cb[m * 2048 + ct * 256 + lane * 4] = o[ct];
        lred[m][lane] = lsum;
    }
    __syncthreads();
    if (h == 0) {
#pragma unroll
        for (int ct = 0; ct < 8; ++ct)
            o[ct] += *(const f32x4*)&cb[m * 2048 + ct * 256 + lane * 4];
        lsum += lred[m][lane];
#pragma unroll
        for (int ct = 0; ct < 8; ++ct)
            *(f32x4*)&cb[m * 2048 + ct * 256 + lane * 4] = o[ct];
        lred[m][lane] = lsum;
    }
    __syncthreads();
    if (h == 1) {
#pragma unroll
        for (int ct = 0; ct < 8; ++ct)
            o[ct] = *(const f32x4*)&cb[m * 2048 + ct * 256 + lane * 4];
        lsum = lred[m][lane];
    }

    float lf = lsum;
    lf += __shfl_xor(lf, 16);
    lf += __shfl_xor(lf, 32);
    const float inv = 1.0f / lf;

    f16x4 yf[8];
#pragma unroll
    for (int ct = 0; ct < 8; ++ct)
#pragma unroll
        for (int r = 0; r < 4; ++r)
            yf[ct][r] = (_Float16)(o[ct][r] * inv);

    const int row = (tIdx0 + m) * 16 + t;
#pragma unroll 2
    for (int ci = 0; ci < 8; ++ci) {
        const int ctile = h * 8 + ci;
        union { f16x8 v8; f16x4 v4[2]; } w[4];
#pragma unroll
        for (int pp = 0; pp < 4; ++pp)
            w[pp].v8 = *(const f16x8*)(wfT_f + ctile * 2048 + lane * 32 + pp * 8);
        f32x4 acc = zero;
#pragma unroll
        for (int kc2 = 0; kc2 < 8; ++kc2)
            acc = MFMA_F16(w[kc2 >> 1].v4[kc2 & 1], yf[kc2], acc);
        const int col = ctile * 16 + q * 4;
        f32x4 xv = *(const f32x4*)(x + row * 256 + col);
        *(f32x4*)(out + row * 256 + col) = acc + xv;
    }
}

// ---------------------------------------------------------------------------
extern "C" void kernel_launch(void* const* d_in, const int* in_sizes, int n_in,
                              void* d_out, int out_size, void* d_ws, size_t ws_size,
                              hipStream_t stream) {
    const float* x  = (const float*)d_in[0];
    const float* wt = (const float*)d_in[1];
    const float* wp = (const float*)d_in[2];
    const float* wg = (const float*)d_in[3];
    const float* wf = (const float*)d_in[4];
    float* out = (float*)d_out;

    _Float16* ws      = (_Float16*)d_ws;
    _Float16* wt_f    = ws;               //  98304
    _Float16* wfT_f   = ws + 98304;       //  32768
    _Float16* theta_f = ws + 131072;      //  3211264
    _Float16* phi_f   = ws + 3342336;     //  1605632
    short*    g_f     = (short*)(ws + 4947968);  // 1605632
    // total 6553600 halves = ~13.1 MB

    k_prep<<<dim3(64),     256, 0, stream>>>(wt, wp, wg, wf, wt_f, wfT_f);
    k_proj<<<dim3(392, 3), 256, 0, stream>>>(x, wt_f, theta_f, phi_f, g_f);
    k_attn<<<dim3(784),    256, 0, stream>>>(theta_f, phi_f, g_f, wfT_f, x, out);
}